// Round 4
// baseline (1808.186 us; speedup 1.0000x reference)
//
#include <hip/hip_runtime.h>
#include <cstdint>
#include <cstddef>

typedef unsigned short u16;
typedef unsigned int u32;

static constexpr int CB = 4;
static constexpr int CT = 8192;
static constexpr int CD = 512;
static constexpr int CH = 8;
static constexpr int CDH = 64;
static constexpr int CTE = 2048;
static constexpr int CD2 = 1024;

__device__ __forceinline__ float b2f(u16 u) {
    return __uint_as_float(((u32)u) << 16);
}
__device__ __forceinline__ u16 f2b(float f) {
    u32 i = __float_as_uint(f);
    i = i + 0x7fffu + ((i >> 16) & 1u);   // round-to-nearest-even
    return (u16)(i >> 16);
}

// ---------------------------------------------------------------- zero
__global__ __launch_bounds__(256) void zero_kernel(float* __restrict__ p, int n) {
    int i = blockIdx.x * 256 + threadIdx.x;
    if (i < n) p[i] = 0.0f;
}

// ---------------------------------------------------------------- row stats of fp32 x
__global__ __launch_bounds__(256) void rowstats_f32(const float* __restrict__ x,
        float2* __restrict__ stats)
{
    const int row = blockIdx.x;
    const int tid = threadIdx.x;
    const float2 p = ((const float2*)(x + (size_t)row * CD))[tid];
    float s = p.x + p.y;
    float sq = p.x * p.x + p.y * p.y;
#pragma unroll
    for (int m = 1; m < 64; m <<= 1) { s += __shfl_xor(s, m); sq += __shfl_xor(sq, m); }
    __shared__ float red[8];
    const int wid = tid >> 6;
    if ((tid & 63) == 0) { red[wid] = s; red[wid + 4] = sq; }
    __syncthreads();
    if (tid == 0) {
        s = red[0] + red[1] + red[2] + red[3];
        sq = red[4] + red[5] + red[6] + red[7];
        const float mu = s * (1.0f / CD);
        float var = sq * (1.0f / CD) - mu * mu;
        var = fmaxf(var, 0.0f);
        stats[row] = make_float2(mu, rsqrtf(var + 1e-5f));
    }
}

// ---------------------------------------------------------------- row stats of bf16 y
__global__ __launch_bounds__(256) void rowstats_b16(const u16* __restrict__ y,
        float2* __restrict__ stats)
{
    const int row = blockIdx.x;
    const int tid = threadIdx.x;
    const u32 p = ((const u32*)(y + (size_t)row * CD))[tid];
    const float x0 = b2f((u16)(p & 0xffff));
    const float x1 = b2f((u16)(p >> 16));
    float s = x0 + x1;
    float sq = x0 * x0 + x1 * x1;
#pragma unroll
    for (int m = 1; m < 64; m <<= 1) { s += __shfl_xor(s, m); sq += __shfl_xor(sq, m); }
    __shared__ float red[8];
    const int wid = tid >> 6;
    if ((tid & 63) == 0) { red[wid] = s; red[wid + 4] = sq; }
    __syncthreads();
    if (tid == 0) {
        s = red[0] + red[1] + red[2] + red[3];
        sq = red[4] + red[5] + red[6] + red[7];
        const float mu = s * (1.0f / CD);
        float var = sq * (1.0f / CD) - mu * mu;
        var = fmaxf(var, 0.0f);
        stats[row] = make_float2(mu, rsqrtf(var + 1e-5f));
    }
}

// ---------------------------------------------------------------- fused GEMM
// C[M,N] = op(A)[M,K] @ W[K,N] + bias (+epilogue), M=32768, N=K=512, fp32 W.
// mode 0 (q):  A=x fp32, op=LN1(stats,gA,bA); out bf16
// mode 1 (k):  same + epilogue += (1-mask[row])*-1e6; out bf16
// mode 2 (v):  same + epilogue *= mask[row]; out bf16
// mode 3 (o):  A=y bf16, op=LN2(stats,gA,bA) -> *(1+eo.scale)+eo.shift -> silu;
//              epilogue += xres[row,col]; out fp32
#define BM 64
#define BN 64
#define BK 32

__global__ __launch_bounds__(256) void gemm_fused(
    const void* __restrict__ Av, const float* __restrict__ W,
    const float* __restrict__ bias, void* __restrict__ Cv,
    const float* __restrict__ mask, const float* __restrict__ xres,
    const float2* __restrict__ stats,
    const float* __restrict__ gA, const float* __restrict__ bA,
    const float* __restrict__ eo, int mode)
{
    __shared__ float As[BK][BM + 4];
    __shared__ float Bs[BK][BN + 4];
    const int tid = threadIdx.x;
    const int mt0 = blockIdx.y * BM;
    const int nt0 = blockIdx.x * BN;
    const int ti = tid >> 4;          // 0..15
    const int tj = tid & 15;          // 0..15
    const int am = tid >> 2;          // 0..63 A row in tile
    const int ak = (tid & 3) * 8;     // 0,8,16,24 A k-offset
    const int bk = tid >> 3;          // 0..31 B k row
    const int bn = (tid & 7) * 8;     // 0..56 B col offset
    float acc[4][4];
#pragma unroll
    for (int r = 0; r < 4; r++)
#pragma unroll
        for (int c = 0; c < 4; c++) acc[r][c] = 0.0f;

    const int arow = mt0 + am;
    const float2 st = stats[arow];
    const float mu = st.x, rs = st.y;
    const int eb = arow >> 13;        // batch index (T=8192 rows per batch)

    for (int k0 = 0; k0 < CD; k0 += BK) {
        float a[8];
        const float4 g0 = *(const float4*)(gA + k0 + ak);
        const float4 g1 = *(const float4*)(gA + k0 + ak + 4);
        const float4 e0 = *(const float4*)(bA + k0 + ak);
        const float4 e1 = *(const float4*)(bA + k0 + ak + 4);
        const float g[8] = { g0.x, g0.y, g0.z, g0.w, g1.x, g1.y, g1.z, g1.w };
        const float be[8] = { e0.x, e0.y, e0.z, e0.w, e1.x, e1.y, e1.z, e1.w };
        if (mode != 3) {
            const float4 a0 = *(const float4*)((const float*)Av + (size_t)arow * CD + k0 + ak);
            const float4 a1 = *(const float4*)((const float*)Av + (size_t)arow * CD + k0 + ak + 4);
            a[0] = a0.x; a[1] = a0.y; a[2] = a0.z; a[3] = a0.w;
            a[4] = a1.x; a[5] = a1.y; a[6] = a1.z; a[7] = a1.w;
#pragma unroll
            for (int j = 0; j < 8; j++) {
                const float t = (a[j] - mu) * rs;
                a[j] = fmaf(t, g[j], be[j]);
            }
        } else {
            const uint4 yv = *(const uint4*)((const u16*)Av + (size_t)arow * CD + k0 + ak);
            a[0] = b2f((u16)(yv.x & 0xffff)); a[1] = b2f((u16)(yv.x >> 16));
            a[2] = b2f((u16)(yv.y & 0xffff)); a[3] = b2f((u16)(yv.y >> 16));
            a[4] = b2f((u16)(yv.z & 0xffff)); a[5] = b2f((u16)(yv.z >> 16));
            a[6] = b2f((u16)(yv.w & 0xffff)); a[7] = b2f((u16)(yv.w >> 16));
            const float* eob = eo + (size_t)eb * CD2 + k0 + ak;
            const float4 s0 = *(const float4*)(eob);
            const float4 s1 = *(const float4*)(eob + 4);
            const float4 h0 = *(const float4*)(eob + CD);
            const float4 h1 = *(const float4*)(eob + CD + 4);
            const float sc[8] = { s0.x, s0.y, s0.z, s0.w, s1.x, s1.y, s1.z, s1.w };
            const float sh[8] = { h0.x, h0.y, h0.z, h0.w, h1.x, h1.y, h1.z, h1.w };
#pragma unroll
            for (int j = 0; j < 8; j++) {
                float t = (a[j] - mu) * rs;
                t = fmaf(t, g[j], be[j]);                 // LN2
                t = fmaf(t, sc[j], t + sh[j]);            // *(1+scale)+shift
                a[j] = t / (1.0f + __expf(-t));           // silu
            }
        }
        const float4 b0 = *(const float4*)(W + (size_t)(k0 + bk) * CD + nt0 + bn);
        const float4 b1 = *(const float4*)(W + (size_t)(k0 + bk) * CD + nt0 + bn + 4);
        __syncthreads();
#pragma unroll
        for (int j = 0; j < 8; j++) As[ak + j][am] = a[j];
        *(float4*)&Bs[bk][bn] = b0;
        *(float4*)&Bs[bk][bn + 4] = b1;
        __syncthreads();
#pragma unroll
        for (int kk = 0; kk < BK; kk++) {
            const float4 a4 = *(const float4*)&As[kk][ti * 4];
            const float4 b4 = *(const float4*)&Bs[kk][tj * 4];
            const float ar[4] = { a4.x, a4.y, a4.z, a4.w };
            const float br[4] = { b4.x, b4.y, b4.z, b4.w };
#pragma unroll
            for (int r = 0; r < 4; r++)
#pragma unroll
                for (int c = 0; c < 4; c++)
                    acc[r][c] = fmaf(ar[r], br[c], acc[r][c]);
        }
    }

    const int col0 = nt0 + tj * 4;
    const float4 bb = *(const float4*)(bias + col0);
    const float bvv[4] = { bb.x, bb.y, bb.z, bb.w };
    if (mode == 3) {
#pragma unroll
        for (int r = 0; r < 4; r++) {
            const int row = mt0 + ti * 4 + r;
            const float4 xr = *(const float4*)(xres + (size_t)row * CD + col0);
            float4 o;
            o.x = acc[r][0] + bvv[0] + xr.x;
            o.y = acc[r][1] + bvv[1] + xr.y;
            o.z = acc[r][2] + bvv[2] + xr.z;
            o.w = acc[r][3] + bvv[3] + xr.w;
            *(float4*)((float*)Cv + (size_t)row * CD + col0) = o;
        }
    } else {
#pragma unroll
        for (int r = 0; r < 4; r++) {
            const int row = mt0 + ti * 4 + r;
            float mval = 0.0f;
            if (mode == 1 || mode == 2) mval = mask[row];
            float vals[4];
#pragma unroll
            for (int c = 0; c < 4; c++) {
                float val = acc[r][c] + bvv[c];
                if (mode == 1) val += (1.0f - mval) * -1000000.0f;
                else if (mode == 2) val *= mval;
                vals[c] = val;
            }
            ushort4 o;
            o.x = f2b(vals[0]); o.y = f2b(vals[1]);
            o.z = f2b(vals[2]); o.w = f2b(vals[3]);
            *(ushort4*)((u16*)Cv + (size_t)row * CD + col0) = o;
        }
    }
}

// ---------------------------------------------------------------- q softmax over head dim (64), bf16 in-place
__global__ __launch_bounds__(256) void qsoftmax_kernel(u16* __restrict__ q) {
    const int tid = threadIdx.x;
    const int g = blockIdx.x * 4 + (tid >> 6);
    const int lane = tid & 63;
    const size_t off = (size_t)(g >> 3) * CD + (size_t)(g & 7) * CDH + lane;
    const float xv = b2f(q[off]);
    float m = xv;
#pragma unroll
    for (int s = 1; s < 64; s <<= 1) m = fmaxf(m, __shfl_xor(m, s));
    const float e = __expf(xv - m);
    float sum = e;
#pragma unroll
    for (int s = 1; s < 64; s <<= 1) sum += __shfl_xor(sum, s);
    q[off] = f2b(e / sum);
}

// ---------------------------------------------------------------- k softmax over T: pass 1 partials
// grid = B(4) * chunks(8) * colgroups(8) = 256; block 256
__global__ __launch_bounds__(256) void ksm_partial(const u16* __restrict__ k,
        float* __restrict__ pm, float* __restrict__ ps)
{
    const int bid = blockIdx.x;
    const int b = bid >> 6, ch = (bid >> 3) & 7, cg = bid & 7;
    const int lane = threadIdx.x & 63, r = threadIdx.x >> 6;
    const int c = cg * 64 + lane;
    float m = -3.0e38f, s = 0.0f;
    const u16* base = k + (size_t)b * CT * CD + c;
    for (int t = ch * 1024 + r; t < (ch + 1) * 1024; t += 4) {
        const float xv = b2f(base[(size_t)t * CD]);
        const float nm = fmaxf(m, xv);
        s = s * __expf(m - nm) + __expf(xv - nm);
        m = nm;
    }
    __shared__ float Lm[4][64], Ls[4][64];
    Lm[r][lane] = m; Ls[r][lane] = s;
    __syncthreads();
    if (r == 0) {
        float M = Lm[0][lane];
#pragma unroll
        for (int qq = 1; qq < 4; qq++) M = fmaxf(M, Lm[qq][lane]);
        float S = 0.0f;
#pragma unroll
        for (int qq = 0; qq < 4; qq++) S += Ls[qq][lane] * __expf(Lm[qq][lane] - M);
        pm[((size_t)b * CD + c) * 8 + ch] = M;
        ps[((size_t)b * CD + c) * 8 + ch] = S;
    }
}

// pass 2: combine partials + normalize in place
// grid = B(4) * colgroups(8) * tchunks(16) = 512; block 256
__global__ __launch_bounds__(256) void ksm_norm(u16* __restrict__ k,
        const float* __restrict__ pm, const float* __restrict__ ps)
{
    const int bid = blockIdx.x;
    const int b = bid >> 7, cg = (bid >> 4) & 7, tch = bid & 15;
    const int tid = threadIdx.x;
    __shared__ float Ms[64], Rs[64];
    if (tid < 64) {
        const int d = cg * 64 + tid;
        const float* pmb = pm + ((size_t)b * CD + d) * 8;
        const float* psb = ps + ((size_t)b * CD + d) * 8;
        float M = pmb[0];
#pragma unroll
        for (int qq = 1; qq < 8; qq++) M = fmaxf(M, pmb[qq]);
        float S = 0.0f;
#pragma unroll
        for (int qq = 0; qq < 8; qq++) S += psb[qq] * __expf(pmb[qq] - M);
        Ms[tid] = M; Rs[tid] = 1.0f / S;
    }
    __syncthreads();
    const int lane = tid & 63, r = tid >> 6;
    const int c = cg * 64 + lane;
    const float M = Ms[lane], R = Rs[lane];
    u16* base = k + (size_t)b * CT * CD + c;
    for (int t = tch * 512 + r; t < (tch + 1) * 512; t += 4) {
        const size_t idx = (size_t)t * CD;
        base[idx] = f2b(__expf(b2f(base[idx]) - M) * R);
    }
}

// ---------------------------------------------------------------- attn = sum_t k (outer) v, per (b,h)
// grid = 32 (b,h) * 16 tchunks = 512; block 256
__global__ __launch_bounds__(256) void attn_kernel(const u16* __restrict__ k,
        const u16* __restrict__ v, float* __restrict__ attn)
{
    const int bid = blockIdx.x;
    const int bh = bid >> 4, ch = bid & 15;
    const int b = bh >> 3, h = bh & 7;
    const int tid = threadIdx.x;
    __shared__ u16 Ks[32][64], Vs[32][64];
    const int ti = tid >> 4, tj = tid & 15;
    const int d0 = ti * 4, l0 = tj * 4;
    const int trow = tid >> 3, cg8 = (tid & 7) * 8;
    float acc[4][4];
#pragma unroll
    for (int r = 0; r < 4; r++)
#pragma unroll
        for (int c = 0; c < 4; c++) acc[r][c] = 0.0f;

    for (int st = 0; st < 16; st++) {
        const int t0 = ch * 512 + st * 32;
        const size_t goff = ((size_t)(b * CT + t0 + trow)) * CD + h * 64 + cg8;
        const uint4 kv4 = *(const uint4*)(k + goff);
        const uint4 vv4 = *(const uint4*)(v + goff);
        __syncthreads();
        *(uint4*)&Ks[trow][cg8] = kv4;
        *(uint4*)&Vs[trow][cg8] = vv4;
        __syncthreads();
#pragma unroll
        for (int tt = 0; tt < 32; tt++) {
            const ushort4 ka = *(const ushort4*)&Ks[tt][d0];
            const ushort4 va = *(const ushort4*)&Vs[tt][l0];
            const float kr[4] = { b2f(ka.x), b2f(ka.y), b2f(ka.z), b2f(ka.w) };
            const float vr[4] = { b2f(va.x), b2f(va.y), b2f(va.z), b2f(va.w) };
#pragma unroll
            for (int r = 0; r < 4; r++)
#pragma unroll
                for (int c = 0; c < 4; c++)
                    acc[r][c] = fmaf(kr[r], vr[c], acc[r][c]);
        }
    }
    float* ab = attn + (size_t)bh * 64 * 64;
#pragma unroll
    for (int r = 0; r < 4; r++)
#pragma unroll
        for (int c = 0; c < 4; c++)
            atomicAdd(&ab[(d0 + r) * 64 + l0 + c], acc[r][c]);
}

// ---------------------------------------------------------------- y = q @ attn per (b,t,h)
// grid = B*T*H/4 = 65536; block 256 (4 waves)
__global__ __launch_bounds__(256) void y_kernel(const u16* __restrict__ q,
        const float* __restrict__ attn, u16* __restrict__ y)
{
    const int tid = threadIdx.x;
    const int g = blockIdx.x * 4 + (tid >> 6);
    const int lane = tid & 63;
    const int row = g >> 3, h = g & 7;
    const int b = row >> 13;   // T = 8192
    const size_t qoff = (size_t)row * CD + (size_t)h * 64 + lane;
    const float qv = b2f(q[qoff]);
    const float* ab = attn + (size_t)(b * CH + h) * 64 * 64;
    float acc = 0.0f;
#pragma unroll 8
    for (int d = 0; d < 64; d++) {
        const float qd = __shfl(qv, d);
        acc = fmaf(qd, ab[d * 64 + lane], acc);
    }
    y[qoff] = f2b(acc);
}

// ---------------------------------------------------------------- emb_out = silu(emb) @ emb_W + emb_b (fp32)
// grid = B*4 = 16; block 256 (one output col per thread)
__global__ __launch_bounds__(256) void embout_kernel(const float* __restrict__ emb,
        const float* __restrict__ embW, const float* __restrict__ embB,
        float* __restrict__ eo)
{
    const int b = blockIdx.x >> 2, jb = blockIdx.x & 3;
    const int j = jb * 256 + threadIdx.x;
    const float* er = emb + (size_t)b * CTE;
    float a0 = 0.0f, a1 = 0.0f, a2 = 0.0f, a3 = 0.0f;
    for (int kk = 0; kk < CTE; kk += 4) {
        float e0 = er[kk + 0];
        float e1 = er[kk + 1];
        float e2 = er[kk + 2];
        float e3 = er[kk + 3];
        e0 = e0 / (1.0f + __expf(-e0));
        e1 = e1 / (1.0f + __expf(-e1));
        e2 = e2 / (1.0f + __expf(-e2));
        e3 = e3 / (1.0f + __expf(-e3));
        a0 = fmaf(e0, embW[(size_t)(kk + 0) * CD2 + j], a0);
        a1 = fmaf(e1, embW[(size_t)(kk + 1) * CD2 + j], a1);
        a2 = fmaf(e2, embW[(size_t)(kk + 2) * CD2 + j], a2);
        a3 = fmaf(e3, embW[(size_t)(kk + 3) * CD2 + j], a3);
    }
    eo[(size_t)b * CD2 + j] = (a0 + a1) + (a2 + a3) + embB[j];
}

// ----------------------------------------------------------------
// All I/O is FP32 (per the reference). Intermediates stored bf16.
// d_out (64 MB fp32 out) doubles as scratch until the final GEMM:
//   R0 = d_out[ 0,32M): bf16 k, then bf16 q (k dead after attn_kernel)
//   R1 = d_out[32M,64M): bf16 v (dead after attn_kernel)
// d_ws (uses ~33.2 MB):
//   ws+0        : y bf16 (32 MB)
//   ws+33554432 : stats  (float2 x 32768, 256 KB)  LN1 row stats of x
//   ws+33816576 : stats2 (256 KB)                  LN2 row stats of y
//   ws+34078720 : attn   (512 KB fp32)
//   ws+34603008 : pm     (64 KB)
//   ws+34668544 : ps     (64 KB)
//   ws+34734080 : eo     (16 KB fp32)
extern "C" void kernel_launch(void* const* d_in, const int* in_sizes, int n_in,
                              void* d_out, int out_size, void* d_ws, size_t ws_size,
                              hipStream_t stream) {
    (void)in_sizes; (void)n_in; (void)out_size; (void)ws_size;
    const float* x    = (const float*)d_in[0];
    const float* emb  = (const float*)d_in[1];
    const float* mask = (const float*)d_in[2];
    const float* gamma= (const float*)d_in[3];
    const float* beta = (const float*)d_in[4];
    const float* Wq   = (const float*)d_in[5];
    const float* bq   = (const float*)d_in[6];
    const float* Wk   = (const float*)d_in[7];
    const float* bk   = (const float*)d_in[8];
    const float* Wv   = (const float*)d_in[9];
    const float* bv   = (const float*)d_in[10];
    const float* embW = (const float*)d_in[11];
    const float* embB = (const float*)d_in[12];
    const float* g2   = (const float*)d_in[13];
    const float* bt2  = (const float*)d_in[14];
    const float* outW = (const float*)d_in[15];
    const float* outb = (const float*)d_in[16];

    char* od = (char*)d_out;
    u16* kq  = (u16*)od;                        // R0: k then q (bf16)
    u16* vb  = (u16*)(od + 33554432);           // R1: v (bf16)
    float* outp = (float*)d_out;

    char* ws = (char*)d_ws;
    u16* ybuf     = (u16*)ws;                   // 32 MB bf16 y
    float2* stats = (float2*)(ws + 33554432);
    float2* stats2= (float2*)(ws + 33816576);
    float* attn   = (float*)(ws + 34078720);
    float* pm     = (float*)(ws + 34603008);
    float* ps     = (float*)(ws + 34668544);
    float* eo     = (float*)(ws + 34734080);

    dim3 gg(CD / BN, (CB * CT) / BM);           // (8, 512)

    rowstats_f32<<<CB * CT, 256, 0, stream>>>(x, stats);
    gemm_fused<<<gg, 256, 0, stream>>>(x, Wk, bk, kq, mask, nullptr,
                                       stats, gamma, beta, nullptr, 1);
    ksm_partial<<<256, 256, 0, stream>>>(kq, pm, ps);
    ksm_norm<<<512, 256, 0, stream>>>(kq, pm, ps);
    gemm_fused<<<gg, 256, 0, stream>>>(x, Wv, bv, vb, mask, nullptr,
                                       stats, gamma, beta, nullptr, 2);
    zero_kernel<<<512, 256, 0, stream>>>(attn, CB * CH * CDH * CDH);
    attn_kernel<<<512, 256, 0, stream>>>(kq, vb, attn);
    // k, v dead -> q into R0
    gemm_fused<<<gg, 256, 0, stream>>>(x, Wq, bq, kq, nullptr, nullptr,
                                       stats, gamma, beta, nullptr, 0);
    qsoftmax_kernel<<<(CB * CT * CH) / 4, 256, 0, stream>>>(kq);
    y_kernel<<<(CB * CT * CH) / 4, 256, 0, stream>>>(kq, attn, ybuf);
    embout_kernel<<<16, 256, 0, stream>>>(emb, embW, embB, eo);
    rowstats_b16<<<CB * CT, 256, 0, stream>>>(ybuf, stats2);
    // final: A=y bf16 with fused LN2+style+silu, +outb, +x residual, fp32 out
    gemm_fused<<<gg, 256, 0, stream>>>(ybuf, outW, outb, outp, nullptr, x,
                                       stats2, g2, bt2, eo, 3);
}

// Round 5
// 1016.954 us; speedup vs baseline: 1.7780x; 1.7780x over previous
//
#include <hip/hip_runtime.h>
#include <cstdint>
#include <cstddef>

typedef unsigned short u16;
typedef unsigned int u32;
typedef __attribute__((ext_vector_type(8))) short short8;   // 8 x bf16 (4 VGPRs)
typedef __attribute__((ext_vector_type(4))) float f32x4;    // MFMA accumulator

static constexpr int CB = 4;
static constexpr int CT = 8192;
static constexpr int CD = 512;
static constexpr int CH = 8;
static constexpr int CDH = 64;
static constexpr int CTE = 2048;
static constexpr int CD2 = 1024;

__device__ __forceinline__ float b2f(u16 u) {
    return __uint_as_float(((u32)u) << 16);
}
__device__ __forceinline__ u16 f2b(float f) {
    u32 i = __float_as_uint(f);
    i = i + 0x7fffu + ((i >> 16) & 1u);   // round-to-nearest-even
    return (u16)(i >> 16);
}

// ---------------------------------------------------------------- zero
__global__ __launch_bounds__(256) void zero_kernel(float* __restrict__ p, int n) {
    int i = blockIdx.x * 256 + threadIdx.x;
    if (i < n) p[i] = 0.0f;
}

// ---------------------------------------------------------------- W[k][n] fp32 -> Wt[n][k] bf16 (4 matrices)
__global__ __launch_bounds__(256) void wconv_kernel(
        const float* __restrict__ W0, const float* __restrict__ W1,
        const float* __restrict__ W2, const float* __restrict__ W3,
        u16* __restrict__ Wt)
{
    const float* W;
    switch (blockIdx.y) {
        case 0: W = W0; break;
        case 1: W = W1; break;
        case 2: W = W2; break;
        default: W = W3; break;
    }
    u16* o = Wt + (size_t)blockIdx.y * CD * CD;
    const int idx = blockIdx.x * 256 + threadIdx.x;   // grid.x = 1024
    const int n = idx >> 9, k = idx & 511;
    o[(size_t)n * CD + k] = f2b(W[(size_t)k * CD + n]);
}

// ---------------------------------------------------------------- LN1: fp32 x -> bf16 xn
__global__ __launch_bounds__(256) void ln1_kernel(const float* __restrict__ x,
        const float* __restrict__ g, const float* __restrict__ bt,
        u16* __restrict__ xn)
{
    const int row = blockIdx.x;
    const int tid = threadIdx.x;
    const float2 p = ((const float2*)(x + (size_t)row * CD))[tid];
    float s = p.x + p.y;
    float sq = p.x * p.x + p.y * p.y;
#pragma unroll
    for (int m = 1; m < 64; m <<= 1) { s += __shfl_xor(s, m); sq += __shfl_xor(sq, m); }
    __shared__ float red[8];
    const int wid = tid >> 6;
    if ((tid & 63) == 0) { red[wid] = s; red[wid + 4] = sq; }
    __syncthreads();
    s = red[0] + red[1] + red[2] + red[3];
    sq = red[4] + red[5] + red[6] + red[7];
    const float mu = s * (1.0f / CD);
    float var = sq * (1.0f / CD) - mu * mu;
    var = fmaxf(var, 0.0f);
    const float rs = rsqrtf(var + 1e-5f);
    const float2 gv = ((const float2*)g)[tid];
    const float2 bv = ((const float2*)bt)[tid];
    const float y0 = (p.x - mu) * rs * gv.x + bv.x;
    const float y1 = (p.y - mu) * rs * gv.y + bv.y;
    ((u32*)(xn + (size_t)row * CD))[tid] = (u32)f2b(y0) | ((u32)f2b(y1) << 16);
}

// ---------------------------------------------------------------- MFMA GEMM
// C[M,N] = A[M,K]bf16 @ Bt[N,K]bf16^T + bias, M=32768, N=K=512.
// mode 0 (q): out bf16
// mode 1 (k): + (1-mask[row])*-1e6, out bf16
// mode 2 (v): * mask[row], out bf16
// mode 3 (o): + xres[row,col], out fp32
// Tile 128x128, BK=32; 4 waves each compute 64x64 via 4x4 mfma_f32_16x16x32_bf16.
// LDS layout [koct][dim ^ koct][8] -- XOR swizzle kills bank conflicts for both
// the b128 staging writes (4 lanes sharing a row-quad) and the b128 frag reads.
__global__ __launch_bounds__(256) void gemm_mfma(
    const u16* __restrict__ A, const u16* __restrict__ Bt,
    const float* __restrict__ bias, void* __restrict__ Cv,
    const float* __restrict__ mask, const float* __restrict__ xres,
    int mode)
{
    __shared__ u16 As[4][128][8];   // 8 KB
    __shared__ u16 Bs[4][128][8];   // 8 KB
    const int tid = threadIdx.x;
    const int wave = tid >> 6, lane = tid & 63;
    const int quad = lane >> 4, l16 = lane & 15;
    const int row0 = blockIdx.y * 128;
    const int col0 = blockIdx.x * 128;
    const int wm = (wave >> 1) * 64, wn = (wave & 1) * 64;

    f32x4 acc[4][4];
#pragma unroll
    for (int mt = 0; mt < 4; mt++)
#pragma unroll
        for (int nt = 0; nt < 4; nt++)
            acc[mt][nt] = (f32x4){0.0f, 0.0f, 0.0f, 0.0f};

    const int koct = tid & 3;        // which 8-k octet this thread stages
    const int sm = tid >> 2;         // 0..63 dim index this thread stages

    for (int k0 = 0; k0 < CD; k0 += 32) {
        const u16* Ab = A + (size_t)(row0 + sm) * CD + k0 + koct * 8;
        const u16* Bb = Bt + (size_t)(col0 + sm) * CD + k0 + koct * 8;
        const uint4 a0 = *(const uint4*)Ab;
        const uint4 a1 = *(const uint4*)(Ab + (size_t)64 * CD);
        const uint4 b0 = *(const uint4*)Bb;
        const uint4 b1 = *(const uint4*)(Bb + (size_t)64 * CD);
        __syncthreads();
        *(uint4*)&As[koct][sm ^ koct][0] = a0;
        *(uint4*)&As[koct][(sm ^ koct) + 64][0] = a1;
        *(uint4*)&Bs[koct][sm ^ koct][0] = b0;
        *(uint4*)&Bs[koct][(sm ^ koct) + 64][0] = b1;
        __syncthreads();
        short8 af[4], bf[4];
#pragma unroll
        for (int mt = 0; mt < 4; mt++)
            af[mt] = *(const short8*)&As[quad][(wm + mt * 16) + (l16 ^ quad)][0];
#pragma unroll
        for (int nt = 0; nt < 4; nt++)
            bf[nt] = *(const short8*)&Bs[quad][(wn + nt * 16) + (l16 ^ quad)][0];
#pragma unroll
        for (int mt = 0; mt < 4; mt++)
#pragma unroll
            for (int nt = 0; nt < 4; nt++)
                acc[mt][nt] = __builtin_amdgcn_mfma_f32_16x16x32_bf16(
                    af[mt], bf[nt], acc[mt][nt], 0, 0, 0);
    }

    // epilogue: lane holds D[row=quad*4+r][col=l16] per tile
#pragma unroll
    for (int mt = 0; mt < 4; mt++) {
        const int rbase = row0 + wm + mt * 16 + quad * 4;
#pragma unroll
        for (int r = 0; r < 4; r++) {
            const int row = rbase + r;
            float mval = 0.0f;
            if (mode == 1 || mode == 2) mval = mask[row];
#pragma unroll
            for (int nt = 0; nt < 4; nt++) {
                const int col = col0 + wn + nt * 16 + l16;
                float val = acc[mt][nt][r] + bias[col];
                if (mode == 1) val += (1.0f - mval) * -1000000.0f;
                else if (mode == 2) val *= mval;
                if (mode == 3) {
                    ((float*)Cv)[(size_t)row * CD + col] =
                        val + xres[(size_t)row * CD + col];
                } else {
                    ((u16*)Cv)[(size_t)row * CD + col] = f2b(val);
                }
            }
        }
    }
}

// ---------------------------------------------------------------- k softmax over T: pass 1 partials
// grid = B(4) * chunks(8) * colgroups(8) = 256; block 256
__global__ __launch_bounds__(256) void ksm_partial(const u16* __restrict__ k,
        float* __restrict__ pm, float* __restrict__ ps)
{
    const int bid = blockIdx.x;
    const int b = bid >> 6, ch = (bid >> 3) & 7, cg = bid & 7;
    const int lane = threadIdx.x & 63, r = threadIdx.x >> 6;
    const int c = cg * 64 + lane;
    float m = -3.0e38f, s = 0.0f;
    const u16* base = k + (size_t)b * CT * CD + c;
    for (int t = ch * 1024 + r; t < (ch + 1) * 1024; t += 4) {
        const float xv = b2f(base[(size_t)t * CD]);
        const float nm = fmaxf(m, xv);
        s = s * __expf(m - nm) + __expf(xv - nm);
        m = nm;
    }
    __shared__ float Lm[4][64], Ls[4][64];
    Lm[r][lane] = m; Ls[r][lane] = s;
    __syncthreads();
    if (r == 0) {
        float M = Lm[0][lane];
#pragma unroll
        for (int qq = 1; qq < 4; qq++) M = fmaxf(M, Lm[qq][lane]);
        float S = 0.0f;
#pragma unroll
        for (int qq = 0; qq < 4; qq++) S += Ls[qq][lane] * __expf(Lm[qq][lane] - M);
        pm[((size_t)b * CD + c) * 8 + ch] = M;
        ps[((size_t)b * CD + c) * 8 + ch] = S;
    }
}

// pass 2: combine partials + normalize in place
// grid = B(4) * colgroups(8) * tchunks(16) = 512; block 256
__global__ __launch_bounds__(256) void ksm_norm(u16* __restrict__ k,
        const float* __restrict__ pm, const float* __restrict__ ps)
{
    const int bid = blockIdx.x;
    const int b = bid >> 7, cg = (bid >> 4) & 7, tch = bid & 15;
    const int tid = threadIdx.x;
    __shared__ float Ms[64], Rs[64];
    if (tid < 64) {
        const int d = cg * 64 + tid;
        const float* pmb = pm + ((size_t)b * CD + d) * 8;
        const float* psb = ps + ((size_t)b * CD + d) * 8;
        float M = pmb[0];
#pragma unroll
        for (int qq = 1; qq < 8; qq++) M = fmaxf(M, pmb[qq]);
        float S = 0.0f;
#pragma unroll
        for (int qq = 0; qq < 8; qq++) S += psb[qq] * __expf(pmb[qq] - M);
        Ms[tid] = M; Rs[tid] = 1.0f / S;
    }
    __syncthreads();
    const int lane = tid & 63, r = tid >> 6;
    const int c = cg * 64 + lane;
    const float M = Ms[lane], R = Rs[lane];
    u16* base = k + (size_t)b * CT * CD + c;
    for (int t = tch * 512 + r; t < (tch + 1) * 512; t += 4) {
        const size_t idx = (size_t)t * CD;
        base[idx] = f2b(__expf(b2f(base[idx]) - M) * R);
    }
}

// ---------------------------------------------------------------- attn = sum_t k (outer) v, per (b,h)
// grid = 32 (b,h) * 16 tchunks = 512; block 256
__global__ __launch_bounds__(256) void attn_kernel(const u16* __restrict__ k,
        const u16* __restrict__ v, float* __restrict__ attn)
{
    const int bid = blockIdx.x;
    const int bh = bid >> 4, ch = bid & 15;
    const int b = bh >> 3, h = bh & 7;
    const int tid = threadIdx.x;
    __shared__ u16 Ks[32][64], Vs[32][64];
    const int ti = tid >> 4, tj = tid & 15;
    const int d0 = ti * 4, l0 = tj * 4;
    const int trow = tid >> 3, cg8 = (tid & 7) * 8;
    float acc[4][4];
#pragma unroll
    for (int r = 0; r < 4; r++)
#pragma unroll
        for (int c = 0; c < 4; c++) acc[r][c] = 0.0f;

    for (int st = 0; st < 16; st++) {
        const int t0 = ch * 512 + st * 32;
        const size_t goff = ((size_t)(b * CT + t0 + trow)) * CD + h * 64 + cg8;
        const uint4 kv4 = *(const uint4*)(k + goff);
        const uint4 vv4 = *(const uint4*)(v + goff);
        __syncthreads();
        *(uint4*)&Ks[trow][cg8] = kv4;
        *(uint4*)&Vs[trow][cg8] = vv4;
        __syncthreads();
#pragma unroll
        for (int tt = 0; tt < 32; tt++) {
            const ushort4 ka = *(const ushort4*)&Ks[tt][d0];
            const ushort4 va = *(const ushort4*)&Vs[tt][l0];
            const float kr[4] = { b2f(ka.x), b2f(ka.y), b2f(ka.z), b2f(ka.w) };
            const float vr[4] = { b2f(va.x), b2f(va.y), b2f(va.z), b2f(va.w) };
#pragma unroll
            for (int r = 0; r < 4; r++)
#pragma unroll
                for (int c = 0; c < 4; c++)
                    acc[r][c] = fmaf(kr[r], vr[c], acc[r][c]);
        }
    }
    float* ab = attn + (size_t)bh * 64 * 64;
#pragma unroll
    for (int r = 0; r < 4; r++)
#pragma unroll
        for (int c = 0; c < 4; c++)
            atomicAdd(&ab[(d0 + r) * 64 + l0 + c], acc[r][c]);
}

// ---------------------------------------------------------------- y = softmax(q) @ attn per (b,t,h)
// q-softmax over Dh=64 fused (in-register). grid = B*T*H/4 = 65536; block 256
__global__ __launch_bounds__(256) void y_kernel(const u16* __restrict__ q,
        const float* __restrict__ attn, u16* __restrict__ y)
{
    const int tid = threadIdx.x;
    const int g = blockIdx.x * 4 + (tid >> 6);
    const int lane = tid & 63;
    const int row = g >> 3, h = g & 7;
    const int b = row >> 13;   // T = 8192
    const size_t qoff = (size_t)row * CD + (size_t)h * 64 + lane;
    const float xv = b2f(q[qoff]);
    float m = xv;
#pragma unroll
    for (int s = 1; s < 64; s <<= 1) m = fmaxf(m, __shfl_xor(m, s));
    const float e = __expf(xv - m);
    float sum = e;
#pragma unroll
    for (int s = 1; s < 64; s <<= 1) sum += __shfl_xor(sum, s);
    const float qs = e / sum;
    const float* ab = attn + (size_t)(b * CH + h) * 64 * 64;
    float acc = 0.0f;
#pragma unroll 8
    for (int d = 0; d < 64; d++) {
        const float qd = __shfl(qs, d);
        acc = fmaf(qd, ab[d * 64 + lane], acc);
    }
    y[qoff] = f2b(acc);
}

// ---------------------------------------------------------------- emb_out = silu(emb) @ emb_W + emb_b (fp32)
__global__ __launch_bounds__(256) void embout_kernel(const float* __restrict__ emb,
        const float* __restrict__ embW, const float* __restrict__ embB,
        float* __restrict__ eo)
{
    const int b = blockIdx.x >> 2, jb = blockIdx.x & 3;
    const int j = jb * 256 + threadIdx.x;
    const float* er = emb + (size_t)b * CTE;
    float a0 = 0.0f, a1 = 0.0f, a2 = 0.0f, a3 = 0.0f;
    for (int kk = 0; kk < CTE; kk += 4) {
        float e0 = er[kk + 0];
        float e1 = er[kk + 1];
        float e2 = er[kk + 2];
        float e3 = er[kk + 3];
        e0 = e0 / (1.0f + __expf(-e0));
        e1 = e1 / (1.0f + __expf(-e1));
        e2 = e2 / (1.0f + __expf(-e2));
        e3 = e3 / (1.0f + __expf(-e3));
        a0 = fmaf(e0, embW[(size_t)(kk + 0) * CD2 + j], a0);
        a1 = fmaf(e1, embW[(size_t)(kk + 1) * CD2 + j], a1);
        a2 = fmaf(e2, embW[(size_t)(kk + 2) * CD2 + j], a2);
        a3 = fmaf(e3, embW[(size_t)(kk + 3) * CD2 + j], a3);
    }
    eo[(size_t)b * CD2 + j] = (a0 + a1) + (a2 + a3) + embB[j];
}

// ---------------------------------------------------------------- LN2 + stylization + silu: y bf16 -> s bf16
__global__ __launch_bounds__(256) void ln2_style_kernel(const u16* __restrict__ y,
        const float* __restrict__ g2, const float* __restrict__ bt2,
        const float* __restrict__ eo, u16* __restrict__ sout)
{
    const int row = blockIdx.x;
    const int tid = threadIdx.x;
    const int b = row >> 13;
    const u32 p = ((const u32*)(y + (size_t)row * CD))[tid];
    const float x0 = b2f((u16)(p & 0xffff));
    const float x1 = b2f((u16)(p >> 16));
    float s = x0 + x1;
    float sq = x0 * x0 + x1 * x1;
#pragma unroll
    for (int m = 1; m < 64; m <<= 1) { s += __shfl_xor(s, m); sq += __shfl_xor(sq, m); }
    __shared__ float red[8];
    const int wid = tid >> 6;
    if ((tid & 63) == 0) { red[wid] = s; red[wid + 4] = sq; }
    __syncthreads();
    s = red[0] + red[1] + red[2] + red[3];
    sq = red[4] + red[5] + red[6] + red[7];
    const float mu = s * (1.0f / CD);
    float var = sq * (1.0f / CD) - mu * mu;
    var = fmaxf(var, 0.0f);
    const float rs = rsqrtf(var + 1e-5f);
    const float2 gv = ((const float2*)g2)[tid];
    const float2 bv = ((const float2*)bt2)[tid];
    const float2 sc = ((const float2*)(eo + (size_t)b * CD2))[tid];
    const float2 sh = ((const float2*)(eo + (size_t)b * CD2 + CD))[tid];
    float h0 = (x0 - mu) * rs * gv.x + bv.x;
    float h1 = (x1 - mu) * rs * gv.y + bv.y;
    h0 = h0 * (1.0f + sc.x) + sh.x;
    h1 = h1 * (1.0f + sc.y) + sh.y;
    const float s0 = h0 / (1.0f + __expf(-h0));
    const float s1 = h1 / (1.0f + __expf(-h1));
    ((u32*)(sout + (size_t)row * CD))[tid] = (u32)f2b(s0) | ((u32)f2b(s1) << 16);
}

// ----------------------------------------------------------------
// Buffers:
//  d_out (64 MB fp32 out) as scratch until final GEMM:
//    R0 [0,32M):  k bf16 -> q bf16 (k dead after attn_kernel)
//    R1 [32M,64M): v bf16 -> y bf16 (v dead after attn_kernel)
//  d_ws (~36.3 MB used):
//    ws+0        : xn bf16 (32 MB) -> s bf16 (xn dead after q-GEMM)
//    ws+33554432 : Wt bf16 x4 [n][k]: Wk,Wv,Wq,outW (2 MB)
//    ws+35651584 : attn (512 KB fp32)
//    ws+36175872 : pm (64 KB)
//    ws+36241408 : ps (64 KB)
//    ws+36306944 : eo (16 KB fp32)
extern "C" void kernel_launch(void* const* d_in, const int* in_sizes, int n_in,
                              void* d_out, int out_size, void* d_ws, size_t ws_size,
                              hipStream_t stream) {
    (void)in_sizes; (void)n_in; (void)out_size; (void)ws_size;
    const float* x    = (const float*)d_in[0];
    const float* emb  = (const float*)d_in[1];
    const float* mask = (const float*)d_in[2];
    const float* gamma= (const float*)d_in[3];
    const float* beta = (const float*)d_in[4];
    const float* Wq   = (const float*)d_in[5];
    const float* bq   = (const float*)d_in[6];
    const float* Wk   = (const float*)d_in[7];
    const float* bk   = (const float*)d_in[8];
    const float* Wv   = (const float*)d_in[9];
    const float* bv   = (const float*)d_in[10];
    const float* embW = (const float*)d_in[11];
    const float* embB = (const float*)d_in[12];
    const float* g2   = (const float*)d_in[13];
    const float* bt2  = (const float*)d_in[14];
    const float* outW = (const float*)d_in[15];
    const float* outb = (const float*)d_in[16];

    char* od = (char*)d_out;
    u16* kq  = (u16*)od;                        // R0: k then q
    u16* vy  = (u16*)(od + 33554432);           // R1: v then y
    float* outp = (float*)d_out;

    char* ws = (char*)d_ws;
    u16* xn   = (u16*)ws;                       // 32 MB, later s
    u16* WtK  = (u16*)(ws + 33554432);
    u16* WtV  = WtK + (size_t)CD * CD;
    u16* WtQ  = WtV + (size_t)CD * CD;
    u16* WtO  = WtQ + (size_t)CD * CD;
    float* attn = (float*)(ws + 35651584);
    float* pm   = (float*)(ws + 36175872);
    float* ps   = (float*)(ws + 36241408);
    float* eo   = (float*)(ws + 36306944);

    dim3 gg(CD / 128, (CB * CT) / 128);         // (4, 256)

    wconv_kernel<<<dim3(1024, 4), 256, 0, stream>>>(Wk, Wv, Wq, outW, WtK);
    ln1_kernel<<<CB * CT, 256, 0, stream>>>(x, gamma, beta, xn);
    zero_kernel<<<512, 256, 0, stream>>>(attn, CB * CH * CDH * CDH);
    embout_kernel<<<16, 256, 0, stream>>>(emb, embW, embB, eo);
    gemm_mfma<<<gg, 256, 0, stream>>>(xn, WtK, bk, kq, mask, nullptr, 1);
    ksm_partial<<<256, 256, 0, stream>>>(kq, pm, ps);
    ksm_norm<<<512, 256, 0, stream>>>(kq, pm, ps);
    gemm_mfma<<<gg, 256, 0, stream>>>(xn, WtV, bv, vy, mask, nullptr, 2);
    attn_kernel<<<512, 256, 0, stream>>>(kq, vy, attn);
    // k, v dead -> q into R0, y into R1
    gemm_mfma<<<gg, 256, 0, stream>>>(xn, WtQ, bq, kq, nullptr, nullptr, 0);
    y_kernel<<<(CB * CT * CH) / 4, 256, 0, stream>>>(kq, attn, vy);
    ln2_style_kernel<<<CB * CT, 256, 0, stream>>>(vy, g2, bt2, eo, xn /* s */);
    gemm_mfma<<<gg, 256, 0, stream>>>(xn /* s */, WtO, outb, outp, nullptr, x, 3);
}

// Round 6
// 786.693 us; speedup vs baseline: 2.2985x; 1.2927x over previous
//
#include <hip/hip_runtime.h>
#include <cstdint>
#include <cstddef>

typedef unsigned short u16;
typedef unsigned int u32;
typedef __attribute__((ext_vector_type(8))) short short8;   // 8 x bf16 (4 VGPRs)
typedef __attribute__((ext_vector_type(4))) float f32x4;    // MFMA accumulator

static constexpr int CB = 4;
static constexpr int CT = 8192;
static constexpr int CD = 512;
static constexpr int CH = 8;
static constexpr int CDH = 64;
static constexpr int CTE = 2048;
static constexpr int CD2 = 1024;

__device__ __forceinline__ float b2f(u16 u) {
    return __uint_as_float(((u32)u) << 16);
}
__device__ __forceinline__ u16 f2b(float f) {
    u32 i = __float_as_uint(f);
    i = i + 0x7fffu + ((i >> 16) & 1u);   // round-to-nearest-even
    return (u16)(i >> 16);
}

// ---------------------------------------------------------------- zero
__global__ __launch_bounds__(256) void zero_kernel(float* __restrict__ p, int n) {
    int i = blockIdx.x * 256 + threadIdx.x;
    if (i < n) p[i] = 0.0f;
}

// ---------------------------------------------------------------- W[k][n] fp32 -> Wt[n][k] bf16, tiled transpose
// grid = dim3(64, 4): 8x8 tiles of 64x64 per matrix; block 256
__global__ __launch_bounds__(256) void wconv_kernel(
        const float* __restrict__ W0, const float* __restrict__ W1,
        const float* __restrict__ W2, const float* __restrict__ W3,
        u16* __restrict__ Wt)
{
    const float* W;
    switch (blockIdx.y) {
        case 0: W = W0; break;
        case 1: W = W1; break;
        case 2: W = W2; break;
        default: W = W3; break;
    }
    u16* o = Wt + (size_t)blockIdx.y * CD * CD;
    const int k0 = (blockIdx.x >> 3) * 64;
    const int n0 = (blockIdx.x & 7) * 64;
    const int tid = threadIdx.x;
    __shared__ u16 tile[64][65];
    const int nn = tid & 63, kq = tid >> 6;
#pragma unroll
    for (int i = 0; i < 16; i++) {
        const int kk = i * 4 + kq;
        tile[kk][nn] = f2b(W[(size_t)(k0 + kk) * CD + n0 + nn]);  // coalesced read
    }
    __syncthreads();
    const int kk2 = tid & 63, nq = tid >> 6;
#pragma unroll
    for (int i = 0; i < 16; i++) {
        const int nn2 = i * 4 + nq;
        o[(size_t)(n0 + nn2) * CD + k0 + kk2] = tile[kk2][nn2];   // coalesced write
    }
}

// ---------------------------------------------------------------- LN1: fp32 x -> bf16 xn
__global__ __launch_bounds__(256) void ln1_kernel(const float* __restrict__ x,
        const float* __restrict__ g, const float* __restrict__ bt,
        u16* __restrict__ xn)
{
    const int row = blockIdx.x;
    const int tid = threadIdx.x;
    const float2 p = ((const float2*)(x + (size_t)row * CD))[tid];
    float s = p.x + p.y;
    float sq = p.x * p.x + p.y * p.y;
#pragma unroll
    for (int m = 1; m < 64; m <<= 1) { s += __shfl_xor(s, m); sq += __shfl_xor(sq, m); }
    __shared__ float red[8];
    const int wid = tid >> 6;
    if ((tid & 63) == 0) { red[wid] = s; red[wid + 4] = sq; }
    __syncthreads();
    s = red[0] + red[1] + red[2] + red[3];
    sq = red[4] + red[5] + red[6] + red[7];
    const float mu = s * (1.0f / CD);
    float var = sq * (1.0f / CD) - mu * mu;
    var = fmaxf(var, 0.0f);
    const float rs = rsqrtf(var + 1e-5f);
    const float2 gv = ((const float2*)g)[tid];
    const float2 bv = ((const float2*)bt)[tid];
    const float y0 = (p.x - mu) * rs * gv.x + bv.x;
    const float y1 = (p.y - mu) * rs * gv.y + bv.y;
    ((u32*)(xn + (size_t)row * CD))[tid] = (u32)f2b(y0) | ((u32)f2b(y1) << 16);
}

// ---------------------------------------------------------------- MFMA GEMM
// C[M,N] = A[M,K]bf16 @ Bt[N,K]bf16^T + bias, M=32768, N=K=512.
// mode 0 (q): out bf16 | mode 1 (k): +(1-mask)*-1e6, bf16 | mode 2 (v): *mask, bf16
// mode 3 (o): + xres, out fp32
// Tile 128x128, BK=32; 4 waves x (4x4 of 16x16x32). XOR-swizzled LDS.
__global__ __launch_bounds__(256) void gemm_mfma(
    const u16* __restrict__ A, const u16* __restrict__ Bt,
    const float* __restrict__ bias, void* __restrict__ Cv,
    const float* __restrict__ mask, const float* __restrict__ xres,
    int mode)
{
    __shared__ u16 As[4][128][8];   // 8 KB
    __shared__ u16 Bs[4][128][8];   // 8 KB
    const int tid = threadIdx.x;
    const int wave = tid >> 6, lane = tid & 63;
    const int quad = lane >> 4, l16 = lane & 15;
    const int row0 = blockIdx.y * 128;
    const int col0 = blockIdx.x * 128;
    const int wm = (wave >> 1) * 64, wn = (wave & 1) * 64;

    f32x4 acc[4][4];
#pragma unroll
    for (int mt = 0; mt < 4; mt++)
#pragma unroll
        for (int nt = 0; nt < 4; nt++)
            acc[mt][nt] = (f32x4){0.0f, 0.0f, 0.0f, 0.0f};

    const int koct = tid & 3;        // which 8-k octet this thread stages
    const int sm = tid >> 2;         // 0..63 dim index this thread stages

    for (int k0 = 0; k0 < CD; k0 += 32) {
        const u16* Ab = A + (size_t)(row0 + sm) * CD + k0 + koct * 8;
        const u16* Bb = Bt + (size_t)(col0 + sm) * CD + k0 + koct * 8;
        const uint4 a0 = *(const uint4*)Ab;
        const uint4 a1 = *(const uint4*)(Ab + (size_t)64 * CD);
        const uint4 b0 = *(const uint4*)Bb;
        const uint4 b1 = *(const uint4*)(Bb + (size_t)64 * CD);
        __syncthreads();
        *(uint4*)&As[koct][sm ^ koct][0] = a0;
        *(uint4*)&As[koct][(sm ^ koct) + 64][0] = a1;
        *(uint4*)&Bs[koct][sm ^ koct][0] = b0;
        *(uint4*)&Bs[koct][(sm ^ koct) + 64][0] = b1;
        __syncthreads();
        short8 af[4], bf[4];
#pragma unroll
        for (int mt = 0; mt < 4; mt++)
            af[mt] = *(const short8*)&As[quad][(wm + mt * 16) + (l16 ^ quad)][0];
#pragma unroll
        for (int nt = 0; nt < 4; nt++)
            bf[nt] = *(const short8*)&Bs[quad][(wn + nt * 16) + (l16 ^ quad)][0];
#pragma unroll
        for (int mt = 0; mt < 4; mt++)
#pragma unroll
            for (int nt = 0; nt < 4; nt++)
                acc[mt][nt] = __builtin_amdgcn_mfma_f32_16x16x32_bf16(
                    af[mt], bf[nt], acc[mt][nt], 0, 0, 0);
    }

    // epilogue: lane holds D[row=quad*4+r][col=l16] per tile
#pragma unroll
    for (int mt = 0; mt < 4; mt++) {
        const int rbase = row0 + wm + mt * 16 + quad * 4;
#pragma unroll
        for (int r = 0; r < 4; r++) {
            const int row = rbase + r;
            float mval = 0.0f;
            if (mode == 1 || mode == 2) mval = mask[row];
#pragma unroll
            for (int nt = 0; nt < 4; nt++) {
                const int col = col0 + wn + nt * 16 + l16;
                float val = acc[mt][nt][r] + bias[col];
                if (mode == 1) val += (1.0f - mval) * -1000000.0f;
                else if (mode == 2) val *= mval;
                if (mode == 3) {
                    ((float*)Cv)[(size_t)row * CD + col] =
                        val + xres[(size_t)row * CD + col];
                } else {
                    ((u16*)Cv)[(size_t)row * CD + col] = f2b(val);
                }
            }
        }
    }
}

// ---------------------------------------------------------------- k softmax over T: pass 1 partials
// grid = B(4) * chunks(8) * colgroups(8) = 256; block 256
__global__ __launch_bounds__(256) void ksm_partial(const u16* __restrict__ k,
        float* __restrict__ pm, float* __restrict__ ps)
{
    const int bid = blockIdx.x;
    const int b = bid >> 6, ch = (bid >> 3) & 7, cg = bid & 7;
    const int lane = threadIdx.x & 63, r = threadIdx.x >> 6;
    const int c = cg * 64 + lane;
    float m = -3.0e38f, s = 0.0f;
    const u16* base = k + (size_t)b * CT * CD + c;
    for (int t = ch * 1024 + r; t < (ch + 1) * 1024; t += 4) {
        const float xv = b2f(base[(size_t)t * CD]);
        const float nm = fmaxf(m, xv);
        s = s * __expf(m - nm) + __expf(xv - nm);
        m = nm;
    }
    __shared__ float Lm[4][64], Ls[4][64];
    Lm[r][lane] = m; Ls[r][lane] = s;
    __syncthreads();
    if (r == 0) {
        float M = Lm[0][lane];
#pragma unroll
        for (int qq = 1; qq < 4; qq++) M = fmaxf(M, Lm[qq][lane]);
        float S = 0.0f;
#pragma unroll
        for (int qq = 0; qq < 4; qq++) S += Ls[qq][lane] * __expf(Lm[qq][lane] - M);
        pm[((size_t)b * CD + c) * 8 + ch] = M;
        ps[((size_t)b * CD + c) * 8 + ch] = S;
    }
}

// pass 2: combine partials + normalize in place
// grid = B(4) * colgroups(8) * tchunks(16) = 512; block 256
__global__ __launch_bounds__(256) void ksm_norm(u16* __restrict__ k,
        const float* __restrict__ pm, const float* __restrict__ ps)
{
    const int bid = blockIdx.x;
    const int b = bid >> 7, cg = (bid >> 4) & 7, tch = bid & 15;
    const int tid = threadIdx.x;
    __shared__ float Ms[64], Rs[64];
    if (tid < 64) {
        const int d = cg * 64 + tid;
        const float* pmb = pm + ((size_t)b * CD + d) * 8;
        const float* psb = ps + ((size_t)b * CD + d) * 8;
        float M = pmb[0];
#pragma unroll
        for (int qq = 1; qq < 8; qq++) M = fmaxf(M, pmb[qq]);
        float S = 0.0f;
#pragma unroll
        for (int qq = 0; qq < 8; qq++) S += psb[qq] * __expf(pmb[qq] - M);
        Ms[tid] = M; Rs[tid] = 1.0f / S;
    }
    __syncthreads();
    const int lane = tid & 63, r = tid >> 6;
    const int c = cg * 64 + lane;
    const float M = Ms[lane], R = Rs[lane];
    u16* base = k + (size_t)b * CT * CD + c;
    for (int t = tch * 512 + r; t < (tch + 1) * 512; t += 4) {
        const size_t idx = (size_t)t * CD;
        base[idx] = f2b(__expf(b2f(base[idx]) - M) * R);
    }
}

// ---------------------------------------------------------------- attn = sum_t k (outer) v, per (b,h)
// grid = 32 (b,h) * 16 tchunks = 512; block 256
__global__ __launch_bounds__(256) void attn_kernel(const u16* __restrict__ k,
        const u16* __restrict__ v, float* __restrict__ attn)
{
    const int bid = blockIdx.x;
    const int bh = bid >> 4, ch = bid & 15;
    const int b = bh >> 3, h = bh & 7;
    const int tid = threadIdx.x;
    __shared__ u16 Ks[32][64], Vs[32][64];
    const int ti = tid >> 4, tj = tid & 15;
    const int d0 = ti * 4, l0 = tj * 4;
    const int trow = tid >> 3, cg8 = (tid & 7) * 8;
    float acc[4][4];
#pragma unroll
    for (int r = 0; r < 4; r++)
#pragma unroll
        for (int c = 0; c < 4; c++) acc[r][c] = 0.0f;

    for (int st = 0; st < 16; st++) {
        const int t0 = ch * 512 + st * 32;
        const size_t goff = ((size_t)(b * CT + t0 + trow)) * CD + h * 64 + cg8;
        const uint4 kv4 = *(const uint4*)(k + goff);
        const uint4 vv4 = *(const uint4*)(v + goff);
        __syncthreads();
        *(uint4*)&Ks[trow][cg8] = kv4;
        *(uint4*)&Vs[trow][cg8] = vv4;
        __syncthreads();
#pragma unroll
        for (int tt = 0; tt < 32; tt++) {
            const ushort4 ka = *(const ushort4*)&Ks[tt][d0];
            const ushort4 va = *(const ushort4*)&Vs[tt][l0];
            const float kr[4] = { b2f(ka.x), b2f(ka.y), b2f(ka.z), b2f(ka.w) };
            const float vr[4] = { b2f(va.x), b2f(va.y), b2f(va.z), b2f(va.w) };
#pragma unroll
            for (int r = 0; r < 4; r++)
#pragma unroll
                for (int c = 0; c < 4; c++)
                    acc[r][c] = fmaf(kr[r], vr[c], acc[r][c]);
        }
    }
    float* ab = attn + (size_t)bh * 64 * 64;
#pragma unroll
    for (int r = 0; r < 4; r++)
#pragma unroll
        for (int c = 0; c < 4; c++)
            atomicAdd(&ab[(d0 + r) * 64 + l0 + c], acc[r][c]);
}

// ---------------------------------------------------------------- y = softmax(q) @ attn per (b,t,h)
__global__ __launch_bounds__(256) void y_kernel(const u16* __restrict__ q,
        const float* __restrict__ attn, u16* __restrict__ y)
{
    const int tid = threadIdx.x;
    const int g = blockIdx.x * 4 + (tid >> 6);
    const int lane = tid & 63;
    const int row = g >> 3, h = g & 7;
    const int b = row >> 13;   // T = 8192
    const size_t qoff = (size_t)row * CD + (size_t)h * 64 + lane;
    const float xv = b2f(q[qoff]);
    float m = xv;
#pragma unroll
    for (int s = 1; s < 64; s <<= 1) m = fmaxf(m, __shfl_xor(m, s));
    const float e = __expf(xv - m);
    float sum = e;
#pragma unroll
    for (int s = 1; s < 64; s <<= 1) sum += __shfl_xor(sum, s);
    const float qs = e / sum;
    const float* ab = attn + (size_t)(b * CH + h) * 64 * 64;
    float acc = 0.0f;
#pragma unroll 8
    for (int d = 0; d < 64; d++) {
        const float qd = __shfl(qs, d);
        acc = fmaf(qd, ab[d * 64 + lane], acc);
    }
    y[qoff] = f2b(acc);
}

// ---------------------------------------------------------------- emb pipeline
// se = silu(emb): 8192 elements
__global__ __launch_bounds__(256) void embsilu_kernel(const float* __restrict__ emb,
        float* __restrict__ se)
{
    const int i = blockIdx.x * 256 + threadIdx.x;
    if (i < CB * CTE) {
        const float e = emb[i];
        se[i] = e / (1.0f + __expf(-e));
    }
}
// eo = embB broadcast per batch: 4096 elements
__global__ __launch_bounds__(256) void eoinit_kernel(const float* __restrict__ embB,
        float* __restrict__ eo)
{
    const int i = blockIdx.x * 256 + threadIdx.x;
    if (i < CB * CD2) eo[i] = embB[i & (CD2 - 1)];
}
// eo += se @ embW for all 4 batches.
// grid = 128 (16 jgroups x 8 kchunks); block 256 = 64 j x 4 ksubs.
// embW read exactly once, coalesced 256 B per wave-step.
__global__ __launch_bounds__(256) void embout2_kernel(const float* __restrict__ se,
        const float* __restrict__ embW, float* __restrict__ eo)
{
    const int jg = blockIdx.x & 15, kc = blockIdx.x >> 4;
    const int tid = threadIdx.x;
    const int jl = tid & 63, kgrp = tid >> 6;
    const int j = jg * 64 + jl;
    const int kbase = kc * 256 + kgrp * 64;
    const float* W = embW + (size_t)kbase * CD2 + j;
    const float* s0 = se + kbase;
    const float* s1 = s0 + CTE;
    const float* s2 = s1 + CTE;
    const float* s3 = s2 + CTE;
    float a0 = 0.0f, a1 = 0.0f, a2 = 0.0f, a3 = 0.0f;
#pragma unroll 8
    for (int kk = 0; kk < 64; kk++) {
        const float w = W[(size_t)kk * CD2];
        a0 = fmaf(s0[kk], w, a0);
        a1 = fmaf(s1[kk], w, a1);
        a2 = fmaf(s2[kk], w, a2);
        a3 = fmaf(s3[kk], w, a3);
    }
    __shared__ float red[4][4][64];   // [kgrp][b][j]
    red[kgrp][0][jl] = a0; red[kgrp][1][jl] = a1;
    red[kgrp][2][jl] = a2; red[kgrp][3][jl] = a3;
    __syncthreads();
    if (tid < 64) {
#pragma unroll
        for (int b = 0; b < 4; b++) {
            const float t = red[0][b][tid] + red[1][b][tid]
                          + red[2][b][tid] + red[3][b][tid];
            atomicAdd(&eo[(size_t)b * CD2 + jg * 64 + tid], t);
        }
    }
}

// ---------------------------------------------------------------- LN2 + stylization + silu: y bf16 -> s bf16
__global__ __launch_bounds__(256) void ln2_style_kernel(const u16* __restrict__ y,
        const float* __restrict__ g2, const float* __restrict__ bt2,
        const float* __restrict__ eo, u16* __restrict__ sout)
{
    const int row = blockIdx.x;
    const int tid = threadIdx.x;
    const int b = row >> 13;
    const u32 p = ((const u32*)(y + (size_t)row * CD))[tid];
    const float x0 = b2f((u16)(p & 0xffff));
    const float x1 = b2f((u16)(p >> 16));
    float s = x0 + x1;
    float sq = x0 * x0 + x1 * x1;
#pragma unroll
    for (int m = 1; m < 64; m <<= 1) { s += __shfl_xor(s, m); sq += __shfl_xor(sq, m); }
    __shared__ float red[8];
    const int wid = tid >> 6;
    if ((tid & 63) == 0) { red[wid] = s; red[wid + 4] = sq; }
    __syncthreads();
    s = red[0] + red[1] + red[2] + red[3];
    sq = red[4] + red[5] + red[6] + red[7];
    const float mu = s * (1.0f / CD);
    float var = sq * (1.0f / CD) - mu * mu;
    var = fmaxf(var, 0.0f);
    const float rs = rsqrtf(var + 1e-5f);
    const float2 gv = ((const float2*)g2)[tid];
    const float2 bv = ((const float2*)bt2)[tid];
    const float2 sc = ((const float2*)(eo + (size_t)b * CD2))[tid];
    const float2 sh = ((const float2*)(eo + (size_t)b * CD2 + CD))[tid];
    float h0 = (x0 - mu) * rs * gv.x + bv.x;
    float h1 = (x1 - mu) * rs * gv.y + bv.y;
    h0 = h0 * (1.0f + sc.x) + sh.x;
    h1 = h1 * (1.0f + sc.y) + sh.y;
    const float s0 = h0 / (1.0f + __expf(-h0));
    const float s1 = h1 / (1.0f + __expf(-h1));
    ((u32*)(sout + (size_t)row * CD))[tid] = (u32)f2b(s0) | ((u32)f2b(s1) << 16);
}

// ----------------------------------------------------------------
// Buffers:
//  d_out (64 MB fp32 out) as scratch until final GEMM:
//    R0 [0,32M):  k bf16 -> q bf16 (k dead after attn_kernel)
//    R1 [32M,64M): v bf16 -> y bf16 (v dead after attn_kernel)
//  d_ws (~36.4 MB used):
//    ws+0        : xn bf16 (32 MB) -> s bf16 (xn dead after q-GEMM)
//    ws+33554432 : Wt bf16 x4 [n][k]: Wk,Wv,Wq,outW (2 MB)
//    ws+35651584 : attn (512 KB fp32)
//    ws+36175872 : pm (64 KB)
//    ws+36241408 : ps (64 KB)
//    ws+36306944 : eo (16 KB fp32)
//    ws+36323328 : se (32 KB fp32, silu(emb))
extern "C" void kernel_launch(void* const* d_in, const int* in_sizes, int n_in,
                              void* d_out, int out_size, void* d_ws, size_t ws_size,
                              hipStream_t stream) {
    (void)in_sizes; (void)n_in; (void)out_size; (void)ws_size;
    const float* x    = (const float*)d_in[0];
    const float* emb  = (const float*)d_in[1];
    const float* mask = (const float*)d_in[2];
    const float* gamma= (const float*)d_in[3];
    const float* beta = (const float*)d_in[4];
    const float* Wq   = (const float*)d_in[5];
    const float* bq   = (const float*)d_in[6];
    const float* Wk   = (const float*)d_in[7];
    const float* bk   = (const float*)d_in[8];
    const float* Wv   = (const float*)d_in[9];
    const float* bv   = (const float*)d_in[10];
    const float* embW = (const float*)d_in[11];
    const float* embB = (const float*)d_in[12];
    const float* g2   = (const float*)d_in[13];
    const float* bt2  = (const float*)d_in[14];
    const float* outW = (const float*)d_in[15];
    const float* outb = (const float*)d_in[16];

    char* od = (char*)d_out;
    u16* kq  = (u16*)od;                        // R0: k then q
    u16* vy  = (u16*)(od + 33554432);           // R1: v then y
    float* outp = (float*)d_out;

    char* ws = (char*)d_ws;
    u16* xn   = (u16*)ws;                       // 32 MB, later s
    u16* WtK  = (u16*)(ws + 33554432);
    u16* WtV  = WtK + (size_t)CD * CD;
    u16* WtQ  = WtV + (size_t)CD * CD;
    u16* WtO  = WtQ + (size_t)CD * CD;
    float* attn = (float*)(ws + 35651584);
    float* pm   = (float*)(ws + 36175872);
    float* ps   = (float*)(ws + 36241408);
    float* eo   = (float*)(ws + 36306944);
    float* se   = (float*)(ws + 36323328);

    dim3 gg(CD / 128, (CB * CT) / 128);         // (4, 256)

    wconv_kernel<<<dim3(64, 4), 256, 0, stream>>>(Wk, Wv, Wq, outW, WtK);
    ln1_kernel<<<CB * CT, 256, 0, stream>>>(x, gamma, beta, xn);
    zero_kernel<<<512, 256, 0, stream>>>(attn, CB * CH * CDH * CDH);
    embsilu_kernel<<<32, 256, 0, stream>>>(emb, se);
    eoinit_kernel<<<16, 256, 0, stream>>>(embB, eo);
    embout2_kernel<<<128, 256, 0, stream>>>(se, embW, eo);
    gemm_mfma<<<gg, 256, 0, stream>>>(xn, WtK, bk, kq, mask, nullptr, 1);
    ksm_partial<<<256, 256, 0, stream>>>(kq, pm, ps);
    ksm_norm<<<512, 256, 0, stream>>>(kq, pm, ps);
    gemm_mfma<<<gg, 256, 0, stream>>>(xn, WtV, bv, vy, mask, nullptr, 2);
    attn_kernel<<<512, 256, 0, stream>>>(kq, vy, attn);
    // k, v dead -> q into R0, y into R1
    gemm_mfma<<<gg, 256, 0, stream>>>(xn, WtQ, bq, kq, nullptr, nullptr, 0);
    y_kernel<<<(CB * CT * CH) / 4, 256, 0, stream>>>(kq, attn, vy);
    ln2_style_kernel<<<CB * CT, 256, 0, stream>>>(vy, g2, bt2, eo, xn /* s */);
    gemm_mfma<<<gg, 256, 0, stream>>>(xn /* s */, WtO, outb, outp, nullptr, x, 3);
}